// Round 12
// baseline (520.483 us; speedup 1.0000x reference)
//
#include <hip/hip_runtime.h>
#include <math.h>

#define TPB 256

// ---- LDS layout (float offsets), lifetime-overlaid. Weights in GLOBAL/L2. ----
// x   [0,784)      flat [28][28], alive until dyn
// c1  [784,1752)   conv7 out [8][11][11] (dead after conv5)
// y   [784,2474)   dyn out [10][13][13] (over c1)
// f   [2474,2564) h [2564,2596) k [2596,2636)
// p3  [0,320) pf [320,570) a1 [570,620) z [620,630)  (x dead after dyn)
#define OX    0
#define OC1   784
#define OY    784
#define OF    2474
#define OH    2564
#define OK2   2596
#define OP3   0
#define OPF   320
#define OA1   570
#define OZ    620
#define SM_TOT 2636   // 10544 B -> wave-capped 8 blocks/CU (32 waves)

// VGPR gate: must stay <=64 (R8:84, R9:88, R11:96 all collapsed the wave cap).
// R7's scalar conv7/conv5/dyn bodies compiled at 40 VGPR — kept verbatim.
// conv2 = R11's lane-per-pixel form (passed correctness): 2 full waves,
// uniform weight loads on the scalar path, shfl-pool, no P2/combine/barrier.
__global__ __launch_bounds__(TPB) void fused_forward(
    const float* __restrict__ x,
    const float* __restrict__ kf_w1, const float* __restrict__ kf_b1,
    const float* __restrict__ kf_w2, const float* __restrict__ kf_b2,
    const float* __restrict__ kf_fc1_w, const float* __restrict__ kf_fc1_b,
    const float* __restrict__ kf_fc2_w, const float* __restrict__ kf_fc2_b,
    const float* __restrict__ conv2_w, const float* __restrict__ conv2_b,
    const float* __restrict__ fc1_w, const float* __restrict__ fc1_b,
    const float* __restrict__ fc2_w, const float* __restrict__ fc2_b,
    float* __restrict__ out)
{
    __shared__ float sm[SM_TOT];
    const int tid = threadIdx.x;
    const int n = blockIdx.x;

    // ---- stage 0: stage x into LDS (float4 flat copy) ----
    {
        const float4* xg = (const float4*)(x + (long long)n * 784);
        float4* d = (float4*)&sm[OX];
        for (int i = tid; i < 196; i += TPB) d[i] = xg[i];
    }
    __syncthreads();

    // ---- conv7 (28->22) + pool (->11) + relu — R7 form, scalar reads ----
    if (tid < 176) {
        int oc = tid & 7;
        int r  = tid >> 3;
        int py = r >> 1;
        int h  = r & 1;
        int cc0 = 10 * h;
        float c[2][12];
        #pragma unroll
        for (int r2 = 0; r2 < 2; ++r2)
            #pragma unroll
            for (int i = 0; i < 12; ++i) c[r2][i] = 0.f;
        float wc[7], wp[7];
        const float* wg = kf_w1 + oc * 49;
        #pragma unroll
        for (int i = 0; i < 7; ++i) wc[i] = wg[i];
        #pragma unroll
        for (int t = 0; t < 8; ++t) {
            const float* xs = &sm[OX + (2 * py + t) * 28 + cc0];
            float row[18];
            #pragma unroll
            for (int i = 0; i < 18; ++i) row[i] = xs[i];
            if (t <= 6) {
                #pragma unroll
                for (int kx = 0; kx < 7; ++kx)
                    #pragma unroll
                    for (int cc = 0; cc < 12; ++cc)
                        c[0][cc] = fmaf(wc[kx], row[cc + kx], c[0][cc]);
            }
            if (t >= 1) {
                #pragma unroll
                for (int kx = 0; kx < 7; ++kx)
                    #pragma unroll
                    for (int cc = 0; cc < 12; ++cc)
                        c[1][cc] = fmaf(wp[kx], row[cc + kx], c[1][cc]);
            }
            #pragma unroll
            for (int i = 0; i < 7; ++i) wp[i] = wc[i];
            if (t < 7) {
                const float* wn = wg + (t + 1) * 7;
                #pragma unroll
                for (int i = 0; i < 7; ++i) wc[i] = wn[i];
            }
        }
        float b = kf_b1[oc];
        #pragma unroll
        for (int j = 0; j < 6; ++j) {
            float m = fmaxf(fmaxf(c[0][2 * j], c[0][2 * j + 1]),
                            fmaxf(c[1][2 * j], c[1][2 * j + 1]));
            sm[OC1 + oc * 121 + py * 11 + 5 * h + j] = fmaxf(m + b, 0.f);
        }
    }
    __syncthreads();

    // ---- conv5 (11->7 used 6x6) + pool (->3) + relu — R7 form ----
    if (tid < 90) {
        int oc = tid % 10, r = tid / 10;
        int py = r / 3, px = r % 3;
        float a00 = 0.f, a01 = 0.f, a10 = 0.f, a11 = 0.f;
        for (int ic = 0; ic < 8; ++ic) {
            float w[25];
            const float* wg = kf_w2 + (oc * 8 + ic) * 25;
            #pragma unroll
            for (int i = 0; i < 25; ++i) w[i] = wg[i];
            const float* xb = &sm[OC1 + ic * 121 + (2 * py) * 11 + 2 * px];
            float cur[6], nxt[6];
            #pragma unroll
            for (int i = 0; i < 6; ++i) cur[i] = xb[i];
            #pragma unroll
            for (int ky = 0; ky < 5; ++ky) {
                const float* xr = xb + (ky + 1) * 11;
                #pragma unroll
                for (int i = 0; i < 6; ++i) nxt[i] = xr[i];
                #pragma unroll
                for (int kx = 0; kx < 5; ++kx) {
                    float wv = w[ky * 5 + kx];
                    a00 = fmaf(wv, cur[kx],     a00);
                    a01 = fmaf(wv, cur[kx + 1], a01);
                    a10 = fmaf(wv, nxt[kx],     a10);
                    a11 = fmaf(wv, nxt[kx + 1], a11);
                }
                #pragma unroll
                for (int i = 0; i < 6; ++i) cur[i] = nxt[i];
            }
        }
        float m = fmaxf(fmaxf(a00, a01), fmaxf(a10, a11)) + kf_b2[oc];
        sm[OF + oc * 9 + py * 3 + px] = fmaxf(m, 0.f);
    }
    __syncthreads();

    // ---- fc 90->32 + relu, then fc 32->40: both wave 0, no barrier between ----
    if (tid < 32) {
        float acc = kf_fc1_b[tid];
        const float* wr = &kf_fc1_w[tid * 90];
        for (int i = 0; i < 90; ++i) acc = fmaf(wr[i], sm[OF + i], acc);
        sm[OH + tid] = fmaxf(acc, 0.f);
    }
    if (tid < 40) {
        float acc = kf_fc2_b[tid];
        const float* wr = &kf_fc2_w[tid * 32];
        #pragma unroll
        for (int i = 0; i < 32; ++i) acc = fmaf(wr[i], sm[OH + i], acc);
        sm[OK2 + tid] = acc;
    }
    __syncthreads();

    // ---- dynamic 2x2 conv + pool + relu -> y [10][13][13] — R7 form ----
    if (tid < 130) {
        int oc = tid % 10, py = tid / 10;
        float k0 = sm[OK2 + oc * 4 + 0], k1 = sm[OK2 + oc * 4 + 1];
        float k2 = sm[OK2 + oc * 4 + 2], k3 = sm[OK2 + oc * 4 + 3];
        const float* x0 = &sm[OX + 2 * py * 28];
        const float* x1 = x0 + 28;
        const float* x2 = x0 + 56;
        float A0 = x0[0], A1 = x1[0], A2 = x2[0];
        float B0 = x0[1], B1 = x1[1], B2 = x2[1];
        #pragma unroll
        for (int j = 0; j < 13; ++j) {
            float C0 = x0[2 * j + 2], C1 = x1[2 * j + 2], C2 = x2[2 * j + 2];
            float c00 = A0 * k0 + B0 * k1 + A1 * k2 + B1 * k3;
            float c01 = B0 * k0 + C0 * k1 + B1 * k2 + C1 * k3;
            float c10 = A1 * k0 + B1 * k1 + A2 * k2 + B2 * k3;
            float c11 = B1 * k0 + C1 * k1 + B2 * k2 + C2 * k3;
            float m = fmaxf(fmaxf(c00, c01), fmaxf(c10, c11));
            sm[OY + oc * 169 + py * 13 + j] = fmaxf(m, 0.f);
            A0 = C0; A1 = C1; A2 = C2;
            if (j < 12) { B0 = x0[2 * j + 3]; B1 = x1[2 * j + 3]; B2 = x2[2 * j + 3]; }
        }
    }
    __syncthreads();

    // ---- conv2 5x5 (8x8 used): lane = pixel, 2 waves, oc split 10/10 ----
    // weights wave-uniform -> scalar loads; pool via shfl_xor; writes p3 direct.
    if (tid < 128) {
        int wave = tid >> 6, lane = tid & 63;
        int rr = lane >> 3, cc = lane & 7;
        int ob = wave * 10;
        float acc[10];
        #pragma unroll
        for (int o = 0; o < 10; ++o) acc[o] = 0.f;
        for (int ic = 0; ic < 10; ++ic) {
            float win[25];
            const float* yb = &sm[OY + ic * 169 + rr * 13 + cc];
            #pragma unroll
            for (int a = 0; a < 5; ++a)
                #pragma unroll
                for (int b = 0; b < 5; ++b) win[a * 5 + b] = yb[a * 13 + b];
            #pragma unroll
            for (int o = 0; o < 10; ++o) {
                const float* wg = conv2_w + ((ob + o) * 10 + ic) * 25;  // uniform
                #pragma unroll
                for (int t = 0; t < 25; ++t)
                    acc[o] = fmaf(wg[t], win[t], acc[o]);
            }
        }
        int py = rr >> 1, px = cc >> 1;
        #pragma unroll
        for (int o = 0; o < 10; ++o) {
            float v = acc[o];
            v = fmaxf(v, __shfl_xor(v, 1));
            v = fmaxf(v, __shfl_xor(v, 8));
            if ((lane & 9) == 0)   // rr,cc both even: quad leader
                sm[OP3 + (ob + o) * 16 + py * 4 + px] = fmaxf(v + conv2_b[ob + o], 0.f);
        }
    }
    __syncthreads();

    // ---- fc 320->50, 5-way k-split (scalar LDS reads) — R7 form ----
    if (tid < 250) {
        int g = tid / 50, o = tid % 50;
        const float* wr = &fc1_w[o * 320 + g * 64];
        const float* pp = &sm[OP3 + g * 64];
        float acc = 0.f;
        #pragma unroll
        for (int i = 0; i < 64; ++i) acc = fmaf(wr[i], pp[i], acc);
        sm[OPF + tid] = acc;
    }
    __syncthreads();

    // ---- tail: all wave 0, barrier-free ----
    if (tid < 50) {
        float a = fc1_b[tid];
        #pragma unroll
        for (int g = 0; g < 5; ++g) a += sm[OPF + g * 50 + tid];
        sm[OA1 + tid] = fmaxf(a, 0.f);
    }
    if (tid < 10) {
        float a = fc2_b[tid];
        const float* wr = &fc2_w[tid * 50];
        #pragma unroll
        for (int i = 0; i < 50; ++i) a = fmaf(wr[i], sm[OA1 + i], a);
        sm[OZ + tid] = a;
    }
    if (tid < 10) {
        float m = sm[OZ + 0];
        #pragma unroll
        for (int i = 1; i < 10; ++i) m = fmaxf(m, sm[OZ + i]);
        float s = 0.f;
        #pragma unroll
        for (int i = 0; i < 10; ++i) s += expf(sm[OZ + i] - m);
        out[n * 10 + tid] = sm[OZ + tid] - m - logf(s);
    }
}

extern "C" void kernel_launch(void* const* d_in, const int* in_sizes, int n_in,
                              void* d_out, int out_size, void* d_ws, size_t ws_size,
                              hipStream_t stream) {
    const float* x        = (const float*)d_in[0];
    const float* kf_w1    = (const float*)d_in[1];
    const float* kf_b1    = (const float*)d_in[2];
    const float* kf_w2    = (const float*)d_in[3];
    const float* kf_b2    = (const float*)d_in[4];
    const float* kf_fc1_w = (const float*)d_in[5];
    const float* kf_fc1_b = (const float*)d_in[6];
    const float* kf_fc2_w = (const float*)d_in[7];
    const float* kf_fc2_b = (const float*)d_in[8];
    const float* conv2_w  = (const float*)d_in[9];
    const float* conv2_b  = (const float*)d_in[10];
    const float* fc1_w    = (const float*)d_in[11];
    const float* fc1_b    = (const float*)d_in[12];
    const float* fc2_w    = (const float*)d_in[13];
    const float* fc2_b    = (const float*)d_in[14];

    const int N = in_sizes[0] / 784;   // 8192

    fused_forward<<<N, TPB, 0, stream>>>(
        x, kf_w1, kf_b1, kf_w2, kf_b2, kf_fc1_w, kf_fc1_b, kf_fc2_w, kf_fc2_b,
        conv2_w, conv2_b, fc1_w, fc1_b, fc2_w, fc2_b, (float*)d_out);
}